// Round 1
// baseline (1215.925 us; speedup 1.0000x reference)
//
#include <hip/hip_runtime.h>
#include <hip/hip_bf16.h>

// Dims (fixed by the reference)
#define B_   8
#define L_   512
#define DIN  128
#define DM   512
#define NLAY 2
#define DI   1024     // d_inner
#define DS   16       // d_state
#define DTR  32       // dt_rank
#define BL   (B_ * L_)   // 4096

// ---------------------------------------------------------------------------
// Generic fp32 GEMM: C[M,N] = A[M,K] * W[N,K]^T (+bias) (+softplus if act==1)
// A row-major with row stride lda; W row-major with row stride ldw; C ldc.
// Tile 64x64, BK=16, 256 threads, 4x4 per thread. Requires M%64==N%64==K%16==0.
// ---------------------------------------------------------------------------
__global__ __launch_bounds__(256) void gemm_bias_act(
    const float* __restrict__ A, int lda,
    const float* __restrict__ W, int ldw,
    const float* __restrict__ bias,
    float* __restrict__ C, int ldc,
    int K, int act)
{
    __shared__ float As[16][68];   // [k][m], stride 68 keeps float4 alignment
    __shared__ float Ws[16][68];   // [k][n]

    const int tid  = threadIdx.x;
    const int tx   = tid & 15;          // n-dir
    const int ty   = tid >> 4;          // m-dir
    const int lrow = tid >> 2;          // 0..63 (tile row for loads)
    const int lk   = (tid & 3) << 2;    // 0,4,8,12

    const float* Ap = A + (blockIdx.y * 64 + lrow) * lda + lk;
    const float* Wp = W + (blockIdx.x * 64 + lrow) * ldw + lk;

    float acc[4][4] = {};

    for (int k0 = 0; k0 < K; k0 += 16) {
        float4 av = *(const float4*)(Ap + k0);
        float4 wv = *(const float4*)(Wp + k0);
        As[lk + 0][lrow] = av.x; As[lk + 1][lrow] = av.y;
        As[lk + 2][lrow] = av.z; As[lk + 3][lrow] = av.w;
        Ws[lk + 0][lrow] = wv.x; Ws[lk + 1][lrow] = wv.y;
        Ws[lk + 2][lrow] = wv.z; Ws[lk + 3][lrow] = wv.w;
        __syncthreads();
#pragma unroll
        for (int k = 0; k < 16; ++k) {
            const float4 a4 = *(const float4*)&As[k][ty << 2];
            const float4 w4 = *(const float4*)&Ws[k][tx << 2];
            acc[0][0] += a4.x * w4.x; acc[0][1] += a4.x * w4.y;
            acc[0][2] += a4.x * w4.z; acc[0][3] += a4.x * w4.w;
            acc[1][0] += a4.y * w4.x; acc[1][1] += a4.y * w4.y;
            acc[1][2] += a4.y * w4.z; acc[1][3] += a4.y * w4.w;
            acc[2][0] += a4.z * w4.x; acc[2][1] += a4.z * w4.y;
            acc[2][2] += a4.z * w4.z; acc[2][3] += a4.z * w4.w;
            acc[3][0] += a4.w * w4.x; acc[3][1] += a4.w * w4.y;
            acc[3][2] += a4.w * w4.z; acc[3][3] += a4.w * w4.w;
        }
        __syncthreads();
    }

    const int row0 = blockIdx.y * 64 + (ty << 2);
    const int col0 = blockIdx.x * 64 + (tx << 2);
    float bi[4] = {0.f, 0.f, 0.f, 0.f};
    if (bias) {
        bi[0] = bias[col0 + 0]; bi[1] = bias[col0 + 1];
        bi[2] = bias[col0 + 2]; bi[3] = bias[col0 + 3];
    }
#pragma unroll
    for (int i = 0; i < 4; ++i) {
        float4 o;
        float v0 = acc[i][0] + bi[0];
        float v1 = acc[i][1] + bi[1];
        float v2 = acc[i][2] + bi[2];
        float v3 = acc[i][3] + bi[3];
        if (act == 1) {  // softplus, numerically safe
            v0 = (v0 > 20.f) ? v0 : log1pf(__expf(v0));
            v1 = (v1 > 20.f) ? v1 : log1pf(__expf(v1));
            v2 = (v2 > 20.f) ? v2 : log1pf(__expf(v2));
            v3 = (v3 > 20.f) ? v3 : log1pf(__expf(v3));
        }
        o.x = v0; o.y = v1; o.z = v2; o.w = v3;
        *(float4*)(C + (row0 + i) * ldc + col0) = o;
    }
}

// ---------------------------------------------------------------------------
// Causal depthwise conv1d (k=4) + bias + silu.
// xz is (BL, 2*DI); channel d comes from column d (xi half). Out xc (BL, DI).
// ---------------------------------------------------------------------------
__global__ __launch_bounds__(256) void conv_silu(
    const float* __restrict__ xz, const float* __restrict__ cw,
    const float* __restrict__ cb, float* __restrict__ xc)
{
    int idx = blockIdx.x * 256 + threadIdx.x;   // over BL*DI
    int d  = idx & (DI - 1);
    int bl = idx >> 10;
    int t  = bl & (L_ - 1);
    int base = (bl - t) * (2 * DI) + d;         // start of batch row, col d
    float acc = cb[d];
    const float* w = cw + d * 4;
    if (t >= 3) {
        acc += w[0] * xz[base + (t - 3) * (2 * DI)];
        acc += w[1] * xz[base + (t - 2) * (2 * DI)];
        acc += w[2] * xz[base + (t - 1) * (2 * DI)];
        acc += w[3] * xz[base + t * (2 * DI)];
    } else {
#pragma unroll
        for (int j = 0; j < 4; ++j) {
            int tt = t - 3 + j;
            if (tt >= 0) acc += w[j] * xz[base + tt * (2 * DI)];
        }
    }
    xc[idx] = acc / (1.f + __expf(-acc));       // silu
}

// ---------------------------------------------------------------------------
// Selective scan. One thread per (b, d, s). State in a register; y via
// width-16 shuffle reduction. 131072 threads = 2048 waves.
// ---------------------------------------------------------------------------
__global__ __launch_bounds__(256) void scan_kernel(
    const float* __restrict__ dt, const float* __restrict__ xc,
    const float* __restrict__ xdbl, const float* __restrict__ A_log,
    float* __restrict__ ys)
{
    int gtid = blockIdx.x * 256 + threadIdx.x;
    int s = gtid & (DS - 1);
    int g = gtid >> 4;            // b*DI + d
    int d = g & (DI - 1);
    int b = g >> 10;
    float a = -__expf(A_log[d * DS + s]);
    float state = 0.f;
    int mbase = b * L_;
    for (int t = 0; t < L_; ++t) {
        int m = mbase + t;
        float dtv = dt[m * DI + d];
        float xv  = xc[m * DI + d];
        float Bv  = xdbl[m * 64 + DTR + s];
        float Cv  = xdbl[m * 64 + DTR + DS + s];
        state = __expf(dtv * a) * state + dtv * xv * Bv;
        float contrib = state * Cv;
        contrib += __shfl_xor(contrib, 1, 16);
        contrib += __shfl_xor(contrib, 2, 16);
        contrib += __shfl_xor(contrib, 4, 16);
        contrib += __shfl_xor(contrib, 8, 16);
        if (s == 0) ys[m * DI + d] = contrib;
    }
}

// ---------------------------------------------------------------------------
// Gate: ys = (ys + xc*Dm) * silu(z), z = second half of xz.
// ---------------------------------------------------------------------------
__global__ __launch_bounds__(256) void gate_kernel(
    float* __restrict__ ys, const float* __restrict__ xc,
    const float* __restrict__ Dm, const float* __restrict__ xz)
{
    int idx = blockIdx.x * 256 + threadIdx.x;
    int d = idx & (DI - 1);
    int m = idx >> 10;
    float z = xz[m * (2 * DI) + DI + d];
    float sz = z / (1.f + __expf(-z));
    ys[idx] = (ys[idx] + xc[idx] * Dm[d]) * sz;
}

// ---------------------------------------------------------------------------
// Mean over L: h (BL, DM) -> hm (B, DM)
// ---------------------------------------------------------------------------
__global__ __launch_bounds__(512) void mean_kernel(
    const float* __restrict__ h, float* __restrict__ hm)
{
    int b = blockIdx.x, d = threadIdx.x;
    float acc = 0.f;
    for (int t = 0; t < L_; ++t) acc += h[(b * L_ + t) * DM + d];
    hm[b * DM + d] = acc * (1.f / (float)L_);
}

// ---------------------------------------------------------------------------
// Classifier: relu(hm @ w1^T + b1) @ w2^T + b2 -> out (B,)
// One block per batch, 64 threads (one per hidden unit).
// ---------------------------------------------------------------------------
__global__ __launch_bounds__(64) void cls_kernel(
    const float* __restrict__ hm, const float* __restrict__ w1,
    const float* __restrict__ b1, const float* __restrict__ w2,
    const float* __restrict__ b2, float* __restrict__ out)
{
    int b = blockIdx.x, j = threadIdx.x;
    const float* hb = hm + b * DM;
    const float* wr = w1 + j * DM;
    float acc = b1[j];
    for (int k = 0; k < DM; k += 4) {
        acc += hb[k] * wr[k] + hb[k+1] * wr[k+1]
             + hb[k+2] * wr[k+2] + hb[k+3] * wr[k+3];
    }
    acc = fmaxf(acc, 0.f);
    float p = acc * w2[j];
#pragma unroll
    for (int off = 32; off; off >>= 1) p += __shfl_down(p, off);
    if (j == 0) out[b] = p + b2[0];
}

// ---------------------------------------------------------------------------
extern "C" void kernel_launch(void* const* d_in, const int* in_sizes, int n_in,
                              void* d_out, int out_size, void* d_ws, size_t ws_size,
                              hipStream_t stream) {
    const float* x          = (const float*)d_in[0];
    const float* proj_in_w  = (const float*)d_in[1];
    const float* proj_in_b  = (const float*)d_in[2];
    const float* in_proj_w  = (const float*)d_in[3];
    const float* conv_w     = (const float*)d_in[4];
    const float* conv_b     = (const float*)d_in[5];
    const float* x_proj_w   = (const float*)d_in[6];
    const float* dt_proj_w  = (const float*)d_in[7];
    const float* dt_proj_b  = (const float*)d_in[8];
    const float* A_log      = (const float*)d_in[9];
    const float* Dm         = (const float*)d_in[10];
    const float* out_proj_w = (const float*)d_in[11];
    const float* cls_w1     = (const float*)d_in[12];
    const float* cls_b1     = (const float*)d_in[13];
    const float* cls_w2     = (const float*)d_in[14];
    const float* cls_b2     = (const float*)d_in[15];
    float* out = (float*)d_out;

    // Workspace layout (floats). Total ~93.4 MB.
    float* ws   = (float*)d_ws;
    float* h    = ws;                       // BL*DM        = 2M floats
    float* xz   = h    + BL * DM;           // BL*2*DI      = 8M
    float* xcb  = xz   + BL * 2 * DI;       // BL*DI        = 4M
    float* xdbl = xcb  + BL * DI;           // BL*64        = 256K
    float* dtb  = xdbl + BL * 64;           // BL*DI        = 4M
    float* ysb  = dtb  + BL * DI;           // BL*DI        = 4M
    float* hm   = ysb  + BL * DI;           // B_*DM        = 4K

    // h = x @ proj_in_w^T + b   (4096x512, K=128)
    gemm_bias_act<<<dim3(DM / 64, BL / 64), 256, 0, stream>>>(
        x, DIN, proj_in_w, DIN, proj_in_b, h, DM, DIN, 0);

    for (int l = 0; l < NLAY; ++l) {
        // xz = h @ in_proj_w^T   (4096x2048, K=512)
        gemm_bias_act<<<dim3(2 * DI / 64, BL / 64), 256, 0, stream>>>(
            h, DM, in_proj_w + l * 2 * DI * DM, DM, nullptr, xz, 2 * DI, DM, 0);
        // xc = silu(causal depthwise conv(xi) + cb)
        conv_silu<<<(BL * DI) / 256, 256, 0, stream>>>(
            xz, conv_w + l * DI * 4, conv_b + l * DI, xcb);
        // x_dbl = xc @ x_proj_w^T  (4096x64, K=1024)
        gemm_bias_act<<<dim3(64 / 64, BL / 64), 256, 0, stream>>>(
            xcb, DI, x_proj_w + l * 64 * DI, DI, nullptr, xdbl, 64, DI, 0);
        // dt = softplus(x_dbl[:, :32] @ dt_proj_w^T + dt_b)  (4096x1024, K=32)
        gemm_bias_act<<<dim3(DI / 64, BL / 64), 256, 0, stream>>>(
            xdbl, 64, dt_proj_w + l * DI * DTR, DTR, dt_proj_b + l * DI,
            dtb, DI, DTR, 1);
        // selective scan -> ys
        scan_kernel<<<(B_ * DI * DS) / 256, 256, 0, stream>>>(
            dtb, xcb, xdbl, A_log + l * DI * DS, ysb);
        // ys = (ys + xc*Dm) * silu(z)
        gate_kernel<<<(BL * DI) / 256, 256, 0, stream>>>(
            ysb, xcb, Dm + l * DI, xz);
        // h = ys @ out_proj_w^T   (4096x512, K=1024)
        gemm_bias_act<<<dim3(DM / 64, BL / 64), 256, 0, stream>>>(
            ysb, DI, out_proj_w + l * DM * DI, DI, nullptr, h, DM, DI, 0);
    }

    // mean over L, then classifier head
    mean_kernel<<<B_, DM, 0, stream>>>(h, hm);
    cls_kernel<<<B_, 64, 0, stream>>>(hm, cls_w1, cls_b1, cls_w2, cls_b2, out);
}

// Round 2
// 849.846 us; speedup vs baseline: 1.4308x; 1.4308x over previous
//
#include <hip/hip_runtime.h>
#include <hip/hip_bf16.h>

// Dims (fixed by the reference)
#define B_   8
#define L_   512
#define DIN  128
#define DM   512
#define NLAY 2
#define DI   1024     // d_inner
#define DS   16       // d_state
#define DTR  32       // dt_rank
#define BL   (B_ * L_)   // 4096

// ---------------------------------------------------------------------------
// Generic fp32 GEMM: C[M,N] = A[M,K] * W[N,K]^T (+bias) (+softplus if act==1)
// Tile 64x64, BK=16, 256 threads, 4x4 per thread. Requires M%64==N%64==K%16==0.
// ---------------------------------------------------------------------------
__global__ __launch_bounds__(256) void gemm_bias_act(
    const float* __restrict__ A, int lda,
    const float* __restrict__ W, int ldw,
    const float* __restrict__ bias,
    float* __restrict__ C, int ldc,
    int K, int act)
{
    __shared__ float As[16][68];   // [k][m]
    __shared__ float Ws[16][68];   // [k][n]

    const int tid  = threadIdx.x;
    const int tx   = tid & 15;          // n-dir
    const int ty   = tid >> 4;          // m-dir
    const int lrow = tid >> 2;          // 0..63
    const int lk   = (tid & 3) << 2;    // 0,4,8,12

    const float* Ap = A + (blockIdx.y * 64 + lrow) * lda + lk;
    const float* Wp = W + (blockIdx.x * 64 + lrow) * ldw + lk;

    float acc[4][4] = {};

    for (int k0 = 0; k0 < K; k0 += 16) {
        float4 av = *(const float4*)(Ap + k0);
        float4 wv = *(const float4*)(Wp + k0);
        As[lk + 0][lrow] = av.x; As[lk + 1][lrow] = av.y;
        As[lk + 2][lrow] = av.z; As[lk + 3][lrow] = av.w;
        Ws[lk + 0][lrow] = wv.x; Ws[lk + 1][lrow] = wv.y;
        Ws[lk + 2][lrow] = wv.z; Ws[lk + 3][lrow] = wv.w;
        __syncthreads();
#pragma unroll
        for (int k = 0; k < 16; ++k) {
            const float4 a4 = *(const float4*)&As[k][ty << 2];
            const float4 w4 = *(const float4*)&Ws[k][tx << 2];
            acc[0][0] += a4.x * w4.x; acc[0][1] += a4.x * w4.y;
            acc[0][2] += a4.x * w4.z; acc[0][3] += a4.x * w4.w;
            acc[1][0] += a4.y * w4.x; acc[1][1] += a4.y * w4.y;
            acc[1][2] += a4.y * w4.z; acc[1][3] += a4.y * w4.w;
            acc[2][0] += a4.z * w4.x; acc[2][1] += a4.z * w4.y;
            acc[2][2] += a4.z * w4.z; acc[2][3] += a4.z * w4.w;
            acc[3][0] += a4.w * w4.x; acc[3][1] += a4.w * w4.y;
            acc[3][2] += a4.w * w4.z; acc[3][3] += a4.w * w4.w;
        }
        __syncthreads();
    }

    const int row0 = blockIdx.y * 64 + (ty << 2);
    const int col0 = blockIdx.x * 64 + (tx << 2);
    float bi[4] = {0.f, 0.f, 0.f, 0.f};
    if (bias) {
        bi[0] = bias[col0 + 0]; bi[1] = bias[col0 + 1];
        bi[2] = bias[col0 + 2]; bi[3] = bias[col0 + 3];
    }
#pragma unroll
    for (int i = 0; i < 4; ++i) {
        float4 o;
        float v0 = acc[i][0] + bi[0];
        float v1 = acc[i][1] + bi[1];
        float v2 = acc[i][2] + bi[2];
        float v3 = acc[i][3] + bi[3];
        if (act == 1) {  // softplus
            v0 = (v0 > 20.f) ? v0 : log1pf(__expf(v0));
            v1 = (v1 > 20.f) ? v1 : log1pf(__expf(v1));
            v2 = (v2 > 20.f) ? v2 : log1pf(__expf(v2));
            v3 = (v3 > 20.f) ? v3 : log1pf(__expf(v3));
        }
        o.x = v0; o.y = v1; o.z = v2; o.w = v3;
        *(float4*)(C + (row0 + i) * ldc + col0) = o;
    }
}

// ---------------------------------------------------------------------------
// Causal depthwise conv1d (k=4) + bias + silu.
// ---------------------------------------------------------------------------
__global__ __launch_bounds__(256) void conv_silu(
    const float* __restrict__ xz, const float* __restrict__ cw,
    const float* __restrict__ cb, float* __restrict__ xc)
{
    int idx = blockIdx.x * 256 + threadIdx.x;   // over BL*DI
    int d  = idx & (DI - 1);
    int bl = idx >> 10;
    int t  = bl & (L_ - 1);
    int base = (bl - t) * (2 * DI) + d;
    float acc = cb[d];
    const float* w = cw + d * 4;
    if (t >= 3) {
        acc += w[0] * xz[base + (t - 3) * (2 * DI)];
        acc += w[1] * xz[base + (t - 2) * (2 * DI)];
        acc += w[2] * xz[base + (t - 1) * (2 * DI)];
        acc += w[3] * xz[base + t * (2 * DI)];
    } else {
#pragma unroll
        for (int j = 0; j < 4; ++j) {
            int tt = t - 3 + j;
            if (tt >= 0) acc += w[j] * xz[base + tt * (2 * DI)];
        }
    }
    xc[idx] = acc / (1.f + __expf(-acc));
}

// ---------------------------------------------------------------------------
// DPP helper: v += value-from-(lane - N) within 16-lane row; OOB reads 0.
// row_shr:N ctrl = 0x110 + N. After shr 1,2,4,8 adds, lane 15 of each row
// holds the row sum.
// ---------------------------------------------------------------------------
template <int CTRL>
__device__ __forceinline__ float dpp_shr_add(float v) {
    int sh = __builtin_amdgcn_update_dpp(0, __float_as_int(v), CTRL, 0xF, 0xF, true);
    return v + __int_as_float(sh);
}

// ---------------------------------------------------------------------------
// Selective scan, LDS-staged. One thread per (b, d, s); block = one b,
// 16 consecutive d (grp = tid>>4), s = tid&15. L processed in chunks of 64
// timesteps staged in LDS; 16-lane s-reduction via DPP row_shr adds (VALU,
// not LDS pipe); y buffered 4-at-a-time and stored coalesced per chunk.
// Grid: 512 blocks x 256.
// ---------------------------------------------------------------------------
__global__ __launch_bounds__(256) void scan_kernel(
    const float* __restrict__ dt, const float* __restrict__ xc,
    const float* __restrict__ xdbl, const float* __restrict__ A_log,
    float* __restrict__ ys)
{
    __shared__ float2 sdx[64][17];   // (dt, xc) [t][grp]  — 8704 B
    __shared__ float2 sbc[64][17];   // (B, C)  [t][s]     — 8704 B
    __shared__ float  sy [16][68];   // y       [grp][t]   — 4352 B

    const int tid  = threadIdx.x;
    const int s    = tid & 15;
    const int grp  = tid >> 4;          // 0..15 → d = d0 + grp
    const int bd0  = blockIdx.x * 16;
    const int b    = bd0 >> 10;
    const int d0   = bd0 & (DI - 1);
    const int mbase = b * L_;

    const int d = d0 + grp;
    const float a = -__expf(A_log[d * DS + s]);
    float state = 0.f;

    // loader mapping: j = column (d or s), tt = base timestep
    const int j  = tid & 15;
    const int tt = tid >> 4;

    for (int c = 0; c < L_ / 64; ++c) {
        const int tc = c * 64;
        __syncthreads();   // previous chunk fully consumed
#pragma unroll
        for (int i = 0; i < 4; ++i) {
            int t = tt + 16 * i;
            int m = mbase + tc + t;
            sdx[t][j] = make_float2(dt[m * DI + d0 + j], xc[m * DI + d0 + j]);
            sbc[t][j] = make_float2(xdbl[m * 64 + DTR + j],
                                    xdbl[m * 64 + DTR + DS + j]);
        }
        __syncthreads();

        for (int t4 = 0; t4 < 64; t4 += 4) {
            float ybuf[4];
#pragma unroll
            for (int u = 0; u < 4; ++u) {
                const int t = t4 + u;
                const float2 dx = sdx[t][grp];   // broadcast within s-group
                const float2 bc = sbc[t][s];
                const float dA = __expf(dx.x * a);
                state = fmaf(dA, state, dx.x * dx.y * bc.x);
                float contrib = state * bc.y;
                contrib = dpp_shr_add<0x111>(contrib);  // + lane-1
                contrib = dpp_shr_add<0x112>(contrib);  // + lane-2
                contrib = dpp_shr_add<0x114>(contrib);  // + lane-4
                contrib = dpp_shr_add<0x118>(contrib);  // + lane-8
                ybuf[u] = contrib;                       // valid in lane s==15
            }
            if (s == 15) *(float4*)&sy[grp][t4] = *(float4*)ybuf;
        }
        __syncthreads();

        // coalesced store of this chunk's y
#pragma unroll
        for (int i = 0; i < 4; ++i) {
            int t = tt + 16 * i;
            ys[(mbase + tc + t) * DI + d0 + j] = sy[j][t];
        }
    }
}

// ---------------------------------------------------------------------------
// Gate: ys = (ys + xc*Dm) * silu(z)
// ---------------------------------------------------------------------------
__global__ __launch_bounds__(256) void gate_kernel(
    float* __restrict__ ys, const float* __restrict__ xc,
    const float* __restrict__ Dm, const float* __restrict__ xz)
{
    int idx = blockIdx.x * 256 + threadIdx.x;
    int d = idx & (DI - 1);
    int m = idx >> 10;
    float z = xz[m * (2 * DI) + DI + d];
    float sz = z / (1.f + __expf(-z));
    ys[idx] = (ys[idx] + xc[idx] * Dm[d]) * sz;
}

// ---------------------------------------------------------------------------
// Mean over L: h (BL, DM) -> hm (B, DM)
// ---------------------------------------------------------------------------
__global__ __launch_bounds__(512) void mean_kernel(
    const float* __restrict__ h, float* __restrict__ hm)
{
    int b = blockIdx.x, d = threadIdx.x;
    float acc = 0.f;
    for (int t = 0; t < L_; ++t) acc += h[(b * L_ + t) * DM + d];
    hm[b * DM + d] = acc * (1.f / (float)L_);
}

// ---------------------------------------------------------------------------
// Classifier head
// ---------------------------------------------------------------------------
__global__ __launch_bounds__(64) void cls_kernel(
    const float* __restrict__ hm, const float* __restrict__ w1,
    const float* __restrict__ b1, const float* __restrict__ w2,
    const float* __restrict__ b2, float* __restrict__ out)
{
    int b = blockIdx.x, j = threadIdx.x;
    const float* hb = hm + b * DM;
    const float* wr = w1 + j * DM;
    float acc = b1[j];
    for (int k = 0; k < DM; k += 4) {
        acc += hb[k] * wr[k] + hb[k+1] * wr[k+1]
             + hb[k+2] * wr[k+2] + hb[k+3] * wr[k+3];
    }
    acc = fmaxf(acc, 0.f);
    float p = acc * w2[j];
#pragma unroll
    for (int off = 32; off; off >>= 1) p += __shfl_down(p, off);
    if (j == 0) out[b] = p + b2[0];
}

// ---------------------------------------------------------------------------
extern "C" void kernel_launch(void* const* d_in, const int* in_sizes, int n_in,
                              void* d_out, int out_size, void* d_ws, size_t ws_size,
                              hipStream_t stream) {
    const float* x          = (const float*)d_in[0];
    const float* proj_in_w  = (const float*)d_in[1];
    const float* proj_in_b  = (const float*)d_in[2];
    const float* in_proj_w  = (const float*)d_in[3];
    const float* conv_w     = (const float*)d_in[4];
    const float* conv_b     = (const float*)d_in[5];
    const float* x_proj_w   = (const float*)d_in[6];
    const float* dt_proj_w  = (const float*)d_in[7];
    const float* dt_proj_b  = (const float*)d_in[8];
    const float* A_log      = (const float*)d_in[9];
    const float* Dm         = (const float*)d_in[10];
    const float* out_proj_w = (const float*)d_in[11];
    const float* cls_w1     = (const float*)d_in[12];
    const float* cls_b1     = (const float*)d_in[13];
    const float* cls_w2     = (const float*)d_in[14];
    const float* cls_b2     = (const float*)d_in[15];
    float* out = (float*)d_out;

    float* ws   = (float*)d_ws;
    float* h    = ws;                       // BL*DM
    float* xz   = h    + BL * DM;           // BL*2*DI
    float* xcb  = xz   + BL * 2 * DI;       // BL*DI
    float* xdbl = xcb  + BL * DI;           // BL*64
    float* dtb  = xdbl + BL * 64;           // BL*DI
    float* ysb  = dtb  + BL * DI;           // BL*DI
    float* hm   = ysb  + BL * DI;           // B_*DM

    gemm_bias_act<<<dim3(DM / 64, BL / 64), 256, 0, stream>>>(
        x, DIN, proj_in_w, DIN, proj_in_b, h, DM, DIN, 0);

    for (int l = 0; l < NLAY; ++l) {
        gemm_bias_act<<<dim3(2 * DI / 64, BL / 64), 256, 0, stream>>>(
            h, DM, in_proj_w + l * 2 * DI * DM, DM, nullptr, xz, 2 * DI, DM, 0);
        conv_silu<<<(BL * DI) / 256, 256, 0, stream>>>(
            xz, conv_w + l * DI * 4, conv_b + l * DI, xcb);
        gemm_bias_act<<<dim3(64 / 64, BL / 64), 256, 0, stream>>>(
            xcb, DI, x_proj_w + l * 64 * DI, DI, nullptr, xdbl, 64, DI, 0);
        gemm_bias_act<<<dim3(DI / 64, BL / 64), 256, 0, stream>>>(
            xdbl, 64, dt_proj_w + l * DI * DTR, DTR, dt_proj_b + l * DI,
            dtb, DI, DTR, 1);
        scan_kernel<<<(B_ * DI) / 16, 256, 0, stream>>>(
            dtb, xcb, xdbl, A_log + l * DI * DS, ysb);
        gate_kernel<<<(BL * DI) / 256, 256, 0, stream>>>(
            ysb, xcb, Dm + l * DI, xz);
        gemm_bias_act<<<dim3(DM / 64, BL / 64), 256, 0, stream>>>(
            ysb, DI, out_proj_w + l * DM * DI, DI, nullptr, h, DM, DI, 0);
    }

    mean_kernel<<<B_, DM, 0, stream>>>(h, hm);
    cls_kernel<<<B_, 64, 0, stream>>>(hm, cls_w1, cls_b1, cls_w2, cls_b2, out);
}

// Round 3
// 538.437 us; speedup vs baseline: 2.2583x; 1.5784x over previous
//
#include <hip/hip_runtime.h>
#include <hip/hip_bf16.h>

// Dims (fixed by the reference)
#define B_   8
#define L_   512
#define DIN  128
#define DM   512
#define NLAY 2
#define DI   1024     // d_inner
#define DS   16       // d_state
#define DTR  32       // dt_rank
#define BL   (B_ * L_)   // 4096

typedef short bf16x8 __attribute__((ext_vector_type(8)));
typedef float floatx4 __attribute__((ext_vector_type(4)));

__device__ __forceinline__ unsigned short f2bf(float f) {
    unsigned int u = __float_as_uint(f);
    unsigned int r = (u + 0x7FFF + ((u >> 16) & 1)) >> 16;   // RNE
    return (unsigned short)r;
}

// ---------------------------------------------------------------------------
// fp32 -> bf16 convert, 8 elements/thread. n must be divisible by 2048.
// ---------------------------------------------------------------------------
__global__ __launch_bounds__(256) void f32_to_bf16(
    const float* __restrict__ in, unsigned short* __restrict__ out)
{
    int i = (blockIdx.x * 256 + threadIdx.x) * 8;
    float4 a = *(const float4*)(in + i);
    float4 b = *(const float4*)(in + i + 4);
    unsigned short o[8];
    o[0] = f2bf(a.x); o[1] = f2bf(a.y); o[2] = f2bf(a.z); o[3] = f2bf(a.w);
    o[4] = f2bf(b.x); o[5] = f2bf(b.y); o[6] = f2bf(b.z); o[7] = f2bf(b.w);
    *(uint4*)(out + i) = *(uint4*)o;
}

// ---------------------------------------------------------------------------
// bf16 MFMA GEMM: C[M,N] = A[M,K] * W[N,K]^T (+bias). A,W bf16; C fp32 and
// optionally bf16 (dual write). Tile 128x128, BK=32, 256 thr (2x2 waves,
// each 64x64 via 4x4 mfma_f32_16x16x32_bf16 tiles). M%128==N%128==K%32==0.
// LDS rows padded to 40 ushorts (80 B): frag reads are 2-way bank = free.
// ---------------------------------------------------------------------------
__global__ __launch_bounds__(256) void gemm_mfma(
    const unsigned short* __restrict__ A,
    const unsigned short* __restrict__ W,
    const float* __restrict__ bias,
    float* __restrict__ C, unsigned short* __restrict__ Cb,
    int N, int K)
{
    __shared__ unsigned short As[128 * 40];
    __shared__ unsigned short Ws[128 * 40];

    const int tid  = threadIdx.x;
    const int row  = tid >> 1;          // 0..127
    const int half = tid & 1;           // 16 ushorts (32 B) each
    const long aBase = (long)(blockIdx.y * 128 + row) * K + half * 16;
    const long wBase = (long)(blockIdx.x * 128 + row) * K + half * 16;
    const int  lbase = row * 40 + half * 16;

    const int lane = tid & 63;
    const int wv   = tid >> 6;
    const int wm   = (wv >> 1) * 64;
    const int wn   = (wv & 1) * 64;
    const int lr   = lane & 15;
    const int q    = lane >> 4;

    floatx4 acc[4][4];
#pragma unroll
    for (int i = 0; i < 4; ++i)
#pragma unroll
        for (int j = 0; j < 4; ++j)
#pragma unroll
            for (int r = 0; r < 4; ++r) acc[i][j][r] = 0.f;

    for (int k0 = 0; k0 < K; k0 += 32) {
        __syncthreads();
        const unsigned short* ap = A + aBase + k0;
        const unsigned short* wp = W + wBase + k0;
        uint4 a0 = *(const uint4*)ap;
        uint4 a1 = *(const uint4*)(ap + 8);
        uint4 w0 = *(const uint4*)wp;
        uint4 w1 = *(const uint4*)(wp + 8);
        *(uint4*)(As + lbase)     = a0;
        *(uint4*)(As + lbase + 8) = a1;
        *(uint4*)(Ws + lbase)     = w0;
        *(uint4*)(Ws + lbase + 8) = w1;
        __syncthreads();

        bf16x8 af[4], bfr[4];
#pragma unroll
        for (int i = 0; i < 4; ++i)
            af[i] = *(const bf16x8*)(As + (wm + i * 16 + lr) * 40 + q * 8);
#pragma unroll
        for (int j = 0; j < 4; ++j)
            bfr[j] = *(const bf16x8*)(Ws + (wn + j * 16 + lr) * 40 + q * 8);
#pragma unroll
        for (int i = 0; i < 4; ++i)
#pragma unroll
            for (int j = 0; j < 4; ++j)
                acc[i][j] = __builtin_amdgcn_mfma_f32_16x16x32_bf16(
                    af[i], bfr[j], acc[i][j], 0, 0, 0);
    }

    float bj[4] = {0.f, 0.f, 0.f, 0.f};
    if (bias) {
#pragma unroll
        for (int j = 0; j < 4; ++j)
            bj[j] = bias[blockIdx.x * 128 + wn + j * 16 + lr];
    }
#pragma unroll
    for (int i = 0; i < 4; ++i) {
#pragma unroll
        for (int r = 0; r < 4; ++r) {
            const int  crow = blockIdx.y * 128 + wm + i * 16 + q * 4 + r;
            const long base = (long)crow * N + blockIdx.x * 128 + wn + lr;
#pragma unroll
            for (int j = 0; j < 4; ++j) {
                float v = acc[i][j][r] + bj[j];
                C[base + j * 16] = v;
                if (Cb) Cb[base + j * 16] = f2bf(v);
            }
        }
    }
}

// ---------------------------------------------------------------------------
// fp32 GEMM (small mats): C[M,N] = A[M,K]*W[N,K]^T (+bias)(+softplus act==1)
// ---------------------------------------------------------------------------
__global__ __launch_bounds__(256) void gemm_bias_act(
    const float* __restrict__ A, int lda,
    const float* __restrict__ W, int ldw,
    const float* __restrict__ bias,
    float* __restrict__ C, int ldc,
    int K, int act)
{
    __shared__ float As[16][68];
    __shared__ float Ws[16][68];

    const int tid  = threadIdx.x;
    const int tx   = tid & 15;
    const int ty   = tid >> 4;
    const int lrow = tid >> 2;
    const int lk   = (tid & 3) << 2;

    const float* Ap = A + (blockIdx.y * 64 + lrow) * lda + lk;
    const float* Wp = W + (blockIdx.x * 64 + lrow) * ldw + lk;

    float acc[4][4] = {};

    for (int k0 = 0; k0 < K; k0 += 16) {
        float4 av = *(const float4*)(Ap + k0);
        float4 wv = *(const float4*)(Wp + k0);
        As[lk + 0][lrow] = av.x; As[lk + 1][lrow] = av.y;
        As[lk + 2][lrow] = av.z; As[lk + 3][lrow] = av.w;
        Ws[lk + 0][lrow] = wv.x; Ws[lk + 1][lrow] = wv.y;
        Ws[lk + 2][lrow] = wv.z; Ws[lk + 3][lrow] = wv.w;
        __syncthreads();
#pragma unroll
        for (int k = 0; k < 16; ++k) {
            const float4 a4 = *(const float4*)&As[k][ty << 2];
            const float4 w4 = *(const float4*)&Ws[k][tx << 2];
            acc[0][0] += a4.x * w4.x; acc[0][1] += a4.x * w4.y;
            acc[0][2] += a4.x * w4.z; acc[0][3] += a4.x * w4.w;
            acc[1][0] += a4.y * w4.x; acc[1][1] += a4.y * w4.y;
            acc[1][2] += a4.y * w4.z; acc[1][3] += a4.y * w4.w;
            acc[2][0] += a4.z * w4.x; acc[2][1] += a4.z * w4.y;
            acc[2][2] += a4.z * w4.z; acc[2][3] += a4.z * w4.w;
            acc[3][0] += a4.w * w4.x; acc[3][1] += a4.w * w4.y;
            acc[3][2] += a4.w * w4.z; acc[3][3] += a4.w * w4.w;
        }
        __syncthreads();
    }

    const int row0 = blockIdx.y * 64 + (ty << 2);
    const int col0 = blockIdx.x * 64 + (tx << 2);
    float bi[4] = {0.f, 0.f, 0.f, 0.f};
    if (bias) {
        bi[0] = bias[col0 + 0]; bi[1] = bias[col0 + 1];
        bi[2] = bias[col0 + 2]; bi[3] = bias[col0 + 3];
    }
#pragma unroll
    for (int i = 0; i < 4; ++i) {
        float4 o;
        float v0 = acc[i][0] + bi[0];
        float v1 = acc[i][1] + bi[1];
        float v2 = acc[i][2] + bi[2];
        float v3 = acc[i][3] + bi[3];
        if (act == 1) {
            v0 = (v0 > 20.f) ? v0 : log1pf(__expf(v0));
            v1 = (v1 > 20.f) ? v1 : log1pf(__expf(v1));
            v2 = (v2 > 20.f) ? v2 : log1pf(__expf(v2));
            v3 = (v3 > 20.f) ? v3 : log1pf(__expf(v3));
        }
        o.x = v0; o.y = v1; o.z = v2; o.w = v3;
        *(float4*)(C + (row0 + i) * ldc + col0) = o;
    }
}

// ---------------------------------------------------------------------------
// Causal depthwise conv1d (k=4) + bias + silu.
// ---------------------------------------------------------------------------
__global__ __launch_bounds__(256) void conv_silu(
    const float* __restrict__ xz, const float* __restrict__ cw,
    const float* __restrict__ cb, float* __restrict__ xc)
{
    int idx = blockIdx.x * 256 + threadIdx.x;
    int d  = idx & (DI - 1);
    int bl = idx >> 10;
    int t  = bl & (L_ - 1);
    int base = (bl - t) * (2 * DI) + d;
    float acc = cb[d];
    const float* w = cw + d * 4;
    if (t >= 3) {
        acc += w[0] * xz[base + (t - 3) * (2 * DI)];
        acc += w[1] * xz[base + (t - 2) * (2 * DI)];
        acc += w[2] * xz[base + (t - 1) * (2 * DI)];
        acc += w[3] * xz[base + t * (2 * DI)];
    } else {
#pragma unroll
        for (int j = 0; j < 4; ++j) {
            int tt = t - 3 + j;
            if (tt >= 0) acc += w[j] * xz[base + tt * (2 * DI)];
        }
    }
    xc[idx] = acc / (1.f + __expf(-acc));
}

// ---------------------------------------------------------------------------
template <int CTRL>
__device__ __forceinline__ float dpp_shr_add(float v) {
    int sh = __builtin_amdgcn_update_dpp(0, __float_as_int(v), CTRL, 0xF, 0xF, true);
    return v + __int_as_float(sh);
}

// ---------------------------------------------------------------------------
// Selective scan, LDS-staged (see R2 notes). Grid: 512 x 256.
// ---------------------------------------------------------------------------
__global__ __launch_bounds__(256) void scan_kernel(
    const float* __restrict__ dt, const float* __restrict__ xc,
    const float* __restrict__ xdbl, const float* __restrict__ A_log,
    float* __restrict__ ys)
{
    __shared__ float2 sdx[64][17];
    __shared__ float2 sbc[64][17];
    __shared__ float  sy [16][68];

    const int tid  = threadIdx.x;
    const int s    = tid & 15;
    const int grp  = tid >> 4;
    const int bd0  = blockIdx.x * 16;
    const int b    = bd0 >> 10;
    const int d0   = bd0 & (DI - 1);
    const int mbase = b * L_;

    const int d = d0 + grp;
    const float a = -__expf(A_log[d * DS + s]);
    float state = 0.f;

    const int j  = tid & 15;
    const int tt = tid >> 4;

    for (int c = 0; c < L_ / 64; ++c) {
        const int tc = c * 64;
        __syncthreads();
#pragma unroll
        for (int i = 0; i < 4; ++i) {
            int t = tt + 16 * i;
            int m = mbase + tc + t;
            sdx[t][j] = make_float2(dt[m * DI + d0 + j], xc[m * DI + d0 + j]);
            sbc[t][j] = make_float2(xdbl[m * 64 + DTR + j],
                                    xdbl[m * 64 + DTR + DS + j]);
        }
        __syncthreads();

        for (int t4 = 0; t4 < 64; t4 += 4) {
            float ybuf[4];
#pragma unroll
            for (int u = 0; u < 4; ++u) {
                const int t = t4 + u;
                const float2 dx = sdx[t][grp];
                const float2 bc = sbc[t][s];
                const float dA = __expf(dx.x * a);
                state = fmaf(dA, state, dx.x * dx.y * bc.x);
                float contrib = state * bc.y;
                contrib = dpp_shr_add<0x111>(contrib);
                contrib = dpp_shr_add<0x112>(contrib);
                contrib = dpp_shr_add<0x114>(contrib);
                contrib = dpp_shr_add<0x118>(contrib);
                ybuf[u] = contrib;
            }
            if (s == 15) *(float4*)&sy[grp][t4] = *(float4*)ybuf;
        }
        __syncthreads();

#pragma unroll
        for (int i = 0; i < 4; ++i) {
            int t = tt + 16 * i;
            ys[(mbase + tc + t) * DI + d0 + j] = sy[j][t];
        }
    }
}

// ---------------------------------------------------------------------------
// Gate: ysb16 = bf16((ys + xc*Dm) * silu(z))  — feeds out_proj MFMA GEMM.
// ---------------------------------------------------------------------------
__global__ __launch_bounds__(256) void gate_kernel(
    const float* __restrict__ ys, const float* __restrict__ xc,
    const float* __restrict__ Dm, const float* __restrict__ xz,
    unsigned short* __restrict__ ysb16)
{
    int idx = blockIdx.x * 256 + threadIdx.x;
    int d = idx & (DI - 1);
    int m = idx >> 10;
    float z = xz[m * (2 * DI) + DI + d];
    float sz = z / (1.f + __expf(-z));
    ysb16[idx] = f2bf((ys[idx] + xc[idx] * Dm[d]) * sz);
}

// ---------------------------------------------------------------------------
__global__ __launch_bounds__(512) void mean_kernel(
    const float* __restrict__ h, float* __restrict__ hm)
{
    int b = blockIdx.x, d = threadIdx.x;
    float acc = 0.f;
    for (int t = 0; t < L_; ++t) acc += h[(b * L_ + t) * DM + d];
    hm[b * DM + d] = acc * (1.f / (float)L_);
}

// ---------------------------------------------------------------------------
__global__ __launch_bounds__(64) void cls_kernel(
    const float* __restrict__ hm, const float* __restrict__ w1,
    const float* __restrict__ b1, const float* __restrict__ w2,
    const float* __restrict__ b2, float* __restrict__ out)
{
    int b = blockIdx.x, j = threadIdx.x;
    const float* hb = hm + b * DM;
    const float* wr = w1 + j * DM;
    float acc = b1[j];
    for (int k = 0; k < DM; k += 4) {
        acc += hb[k] * wr[k] + hb[k+1] * wr[k+1]
             + hb[k+2] * wr[k+2] + hb[k+3] * wr[k+3];
    }
    acc = fmaxf(acc, 0.f);
    float p = acc * w2[j];
#pragma unroll
    for (int off = 32; off; off >>= 1) p += __shfl_down(p, off);
    if (j == 0) out[b] = p + b2[0];
}

// ---------------------------------------------------------------------------
extern "C" void kernel_launch(void* const* d_in, const int* in_sizes, int n_in,
                              void* d_out, int out_size, void* d_ws, size_t ws_size,
                              hipStream_t stream) {
    const float* x          = (const float*)d_in[0];
    const float* proj_in_w  = (const float*)d_in[1];
    const float* proj_in_b  = (const float*)d_in[2];
    const float* in_proj_w  = (const float*)d_in[3];
    const float* conv_w     = (const float*)d_in[4];
    const float* conv_b     = (const float*)d_in[5];
    const float* x_proj_w   = (const float*)d_in[6];
    const float* dt_proj_w  = (const float*)d_in[7];
    const float* dt_proj_b  = (const float*)d_in[8];
    const float* A_log      = (const float*)d_in[9];
    const float* Dm         = (const float*)d_in[10];
    const float* out_proj_w = (const float*)d_in[11];
    const float* cls_w1     = (const float*)d_in[12];
    const float* cls_b1     = (const float*)d_in[13];
    const float* cls_w2     = (const float*)d_in[14];
    const float* cls_b2     = (const float*)d_in[15];
    float* out = (float*)d_out;

    // fp32 workspace
    float* ws   = (float*)d_ws;
    float* h    = ws;                       // BL*DM      = 2M
    float* xz   = h    + BL * DM;           // BL*2*DI    = 8M
    float* xcb  = xz   + BL * 2 * DI;       // BL*DI      = 4M
    float* xdbl = xcb  + BL * DI;           // BL*64      = 256K
    float* dtb  = xdbl + BL * 64;           // BL*DI      = 4M
    float* ysb  = dtb  + BL * DI;           // BL*DI      = 4M
    float* hm   = ysb  + BL * DI;           // B_*DM      = 4K
    // bf16 (ushort) workspace
    unsigned short* u16  = (unsigned short*)(hm + B_ * DM);
    unsigned short* xbf  = u16;                         // BL*DIN  = 512K
    unsigned short* hbf  = xbf  + BL * DIN;             // BL*DM   = 2M
    unsigned short* ysbf = hbf  + BL * DM;              // BL*DI   = 4M
    unsigned short* wpin = ysbf + BL * DI;              // DM*DIN  = 64K
    unsigned short* win  = wpin + DM * DIN;             // 2*2DI*DM= 2M
    unsigned short* wout = win  + NLAY * 2 * DI * DM;   // 2*DM*DI = 1M

    // weight + input conversions (few µs total)
    f32_to_bf16<<<(BL * DIN) / 2048, 256, 0, stream>>>(x, xbf);
    f32_to_bf16<<<(DM * DIN) / 2048, 256, 0, stream>>>(proj_in_w, wpin);
    f32_to_bf16<<<(NLAY * 2 * DI * DM) / 2048, 256, 0, stream>>>(in_proj_w, win);
    f32_to_bf16<<<(NLAY * DM * DI) / 2048, 256, 0, stream>>>(out_proj_w, wout);

    // h = x @ proj_in_w^T + b  (MFMA, dual-write fp32+bf16)
    gemm_mfma<<<dim3(DM / 128, BL / 128), 256, 0, stream>>>(
        xbf, wpin, proj_in_b, h, hbf, DM, DIN);

    for (int l = 0; l < NLAY; ++l) {
        // xz = h @ in_proj_w^T  (MFMA)
        gemm_mfma<<<dim3(2 * DI / 128, BL / 128), 256, 0, stream>>>(
            hbf, win + l * 2 * DI * DM, nullptr, xz, nullptr, 2 * DI, DM);
        conv_silu<<<(BL * DI) / 256, 256, 0, stream>>>(
            xz, conv_w + l * DI * 4, conv_b + l * DI, xcb);
        // x_dbl = xc @ x_proj_w^T  (fp32 — feeds sensitive scan path)
        gemm_bias_act<<<dim3(1, BL / 64), 256, 0, stream>>>(
            xcb, DI, x_proj_w + l * 64 * DI, DI, nullptr, xdbl, 64, DI, 0);
        // dt = softplus(x_dbl[:, :32] @ dt_proj_w^T + dt_b)  (fp32)
        gemm_bias_act<<<dim3(DI / 64, BL / 64), 256, 0, stream>>>(
            xdbl, 64, dt_proj_w + l * DI * DTR, DTR, dt_proj_b + l * DI,
            dtb, DI, DTR, 1);
        scan_kernel<<<(B_ * DI) / 16, 256, 0, stream>>>(
            dtb, xcb, xdbl, A_log + l * DI * DS, ysb);
        gate_kernel<<<(BL * DI) / 256, 256, 0, stream>>>(
            ysb, xcb, Dm + l * DI, xz, ysbf);
        // h = ys @ out_proj_w^T  (MFMA, dual-write)
        gemm_mfma<<<dim3(DM / 128, BL / 128), 256, 0, stream>>>(
            ysbf, wout + l * DM * DI, nullptr, h, hbf, DM, DI);
    }

    mean_kernel<<<B_, DM, 0, stream>>>(h, hm);
    cls_kernel<<<B_, 64, 0, stream>>>(hm, cls_w1, cls_b1, cls_w2, cls_b2, out);
}

// Round 4
// 441.610 us; speedup vs baseline: 2.7534x; 1.2193x over previous
//
#include <hip/hip_runtime.h>
#include <hip/hip_bf16.h>

// Dims (fixed by the reference)
#define B_   8
#define L_   512
#define DIN  128
#define DM   512
#define NLAY 2
#define DI   1024     // d_inner
#define DS   16       // d_state
#define DTR  32       // dt_rank
#define BL   (B_ * L_)   // 4096
#define KS   8           // x_proj split-K slices (K=128 each)

typedef short bf16x8 __attribute__((ext_vector_type(8)));
typedef float floatx4 __attribute__((ext_vector_type(4)));

__device__ __forceinline__ unsigned short f2bf(float f) {
    unsigned int u = __float_as_uint(f);
    unsigned int r = (u + 0x7FFF + ((u >> 16) & 1)) >> 16;   // RNE
    return (unsigned short)r;
}

// ---------------------------------------------------------------------------
// fp32 -> bf16 convert, 8 elements/thread. n must be divisible by 2048.
// ---------------------------------------------------------------------------
__global__ __launch_bounds__(256) void f32_to_bf16(
    const float* __restrict__ in, unsigned short* __restrict__ out)
{
    int i = (blockIdx.x * 256 + threadIdx.x) * 8;
    float4 a = *(const float4*)(in + i);
    float4 b = *(const float4*)(in + i + 4);
    unsigned short o[8];
    o[0] = f2bf(a.x); o[1] = f2bf(a.y); o[2] = f2bf(a.z); o[3] = f2bf(a.w);
    o[4] = f2bf(b.x); o[5] = f2bf(b.y); o[6] = f2bf(b.z); o[7] = f2bf(b.w);
    *(uint4*)(out + i) = *(uint4*)o;
}

// ---------------------------------------------------------------------------
// bf16 MFMA GEMM: C[M,N] = A[M,K] * W[N,K]^T (+bias). Tile 128x128, BK=32.
// ---------------------------------------------------------------------------
__global__ __launch_bounds__(256) void gemm_mfma(
    const unsigned short* __restrict__ A,
    const unsigned short* __restrict__ W,
    const float* __restrict__ bias,
    float* __restrict__ C, unsigned short* __restrict__ Cb,
    int N, int K)
{
    __shared__ unsigned short As[128 * 40];
    __shared__ unsigned short Ws[128 * 40];

    const int tid  = threadIdx.x;
    const int row  = tid >> 1;
    const int half = tid & 1;
    const long aBase = (long)(blockIdx.y * 128 + row) * K + half * 16;
    const long wBase = (long)(blockIdx.x * 128 + row) * K + half * 16;
    const int  lbase = row * 40 + half * 16;

    const int lane = tid & 63;
    const int wv   = tid >> 6;
    const int wm   = (wv >> 1) * 64;
    const int wn   = (wv & 1) * 64;
    const int lr   = lane & 15;
    const int q    = lane >> 4;

    floatx4 acc[4][4];
#pragma unroll
    for (int i = 0; i < 4; ++i)
#pragma unroll
        for (int j = 0; j < 4; ++j)
#pragma unroll
            for (int r = 0; r < 4; ++r) acc[i][j][r] = 0.f;

    for (int k0 = 0; k0 < K; k0 += 32) {
        __syncthreads();
        const unsigned short* ap = A + aBase + k0;
        const unsigned short* wp = W + wBase + k0;
        uint4 a0 = *(const uint4*)ap;
        uint4 a1 = *(const uint4*)(ap + 8);
        uint4 w0 = *(const uint4*)wp;
        uint4 w1 = *(const uint4*)(wp + 8);
        *(uint4*)(As + lbase)     = a0;
        *(uint4*)(As + lbase + 8) = a1;
        *(uint4*)(Ws + lbase)     = w0;
        *(uint4*)(Ws + lbase + 8) = w1;
        __syncthreads();

        bf16x8 af[4], bfr[4];
#pragma unroll
        for (int i = 0; i < 4; ++i)
            af[i] = *(const bf16x8*)(As + (wm + i * 16 + lr) * 40 + q * 8);
#pragma unroll
        for (int j = 0; j < 4; ++j)
            bfr[j] = *(const bf16x8*)(Ws + (wn + j * 16 + lr) * 40 + q * 8);
#pragma unroll
        for (int i = 0; i < 4; ++i)
#pragma unroll
            for (int j = 0; j < 4; ++j)
                acc[i][j] = __builtin_amdgcn_mfma_f32_16x16x32_bf16(
                    af[i], bfr[j], acc[i][j], 0, 0, 0);
    }

    float bj[4] = {0.f, 0.f, 0.f, 0.f};
    if (bias) {
#pragma unroll
        for (int j = 0; j < 4; ++j)
            bj[j] = bias[blockIdx.x * 128 + wn + j * 16 + lr];
    }
#pragma unroll
    for (int i = 0; i < 4; ++i) {
#pragma unroll
        for (int r = 0; r < 4; ++r) {
            const int  crow = blockIdx.y * 128 + wm + i * 16 + q * 4 + r;
            const long base = (long)crow * N + blockIdx.x * 128 + wn + lr;
#pragma unroll
            for (int j = 0; j < 4; ++j) {
                float v = acc[i][j][r] + bj[j];
                C[base + j * 16] = v;
                if (Cb) Cb[base + j * 16] = f2bf(v);
            }
        }
    }
}

// ---------------------------------------------------------------------------
// fp32 GEMM (small mats): C[M,N] = A[M,K]*W[N,K]^T (+bias)(+softplus act==1)
// ---------------------------------------------------------------------------
__global__ __launch_bounds__(256) void gemm_bias_act(
    const float* __restrict__ A, int lda,
    const float* __restrict__ W, int ldw,
    const float* __restrict__ bias,
    float* __restrict__ C, int ldc,
    int K, int act)
{
    __shared__ float As[16][68];
    __shared__ float Ws[16][68];

    const int tid  = threadIdx.x;
    const int tx   = tid & 15;
    const int ty   = tid >> 4;
    const int lrow = tid >> 2;
    const int lk   = (tid & 3) << 2;

    const float* Ap = A + (blockIdx.y * 64 + lrow) * lda + lk;
    const float* Wp = W + (blockIdx.x * 64 + lrow) * ldw + lk;

    float acc[4][4] = {};

    for (int k0 = 0; k0 < K; k0 += 16) {
        float4 av = *(const float4*)(Ap + k0);
        float4 wv = *(const float4*)(Wp + k0);
        As[lk + 0][lrow] = av.x; As[lk + 1][lrow] = av.y;
        As[lk + 2][lrow] = av.z; As[lk + 3][lrow] = av.w;
        Ws[lk + 0][lrow] = wv.x; Ws[lk + 1][lrow] = wv.y;
        Ws[lk + 2][lrow] = wv.z; Ws[lk + 3][lrow] = wv.w;
        __syncthreads();
#pragma unroll
        for (int k = 0; k < 16; ++k) {
            const float4 a4 = *(const float4*)&As[k][ty << 2];
            const float4 w4 = *(const float4*)&Ws[k][tx << 2];
            acc[0][0] += a4.x * w4.x; acc[0][1] += a4.x * w4.y;
            acc[0][2] += a4.x * w4.z; acc[0][3] += a4.x * w4.w;
            acc[1][0] += a4.y * w4.x; acc[1][1] += a4.y * w4.y;
            acc[1][2] += a4.y * w4.z; acc[1][3] += a4.y * w4.w;
            acc[2][0] += a4.z * w4.x; acc[2][1] += a4.z * w4.y;
            acc[2][2] += a4.z * w4.z; acc[2][3] += a4.z * w4.w;
            acc[3][0] += a4.w * w4.x; acc[3][1] += a4.w * w4.y;
            acc[3][2] += a4.w * w4.z; acc[3][3] += a4.w * w4.w;
        }
        __syncthreads();
    }

    const int row0 = blockIdx.y * 64 + (ty << 2);
    const int col0 = blockIdx.x * 64 + (tx << 2);
    float bi[4] = {0.f, 0.f, 0.f, 0.f};
    if (bias) {
        bi[0] = bias[col0 + 0]; bi[1] = bias[col0 + 1];
        bi[2] = bias[col0 + 2]; bi[3] = bias[col0 + 3];
    }
#pragma unroll
    for (int i = 0; i < 4; ++i) {
        float4 o;
        float v0 = acc[i][0] + bi[0];
        float v1 = acc[i][1] + bi[1];
        float v2 = acc[i][2] + bi[2];
        float v3 = acc[i][3] + bi[3];
        if (act == 1) {
            v0 = (v0 > 20.f) ? v0 : log1pf(__expf(v0));
            v1 = (v1 > 20.f) ? v1 : log1pf(__expf(v1));
            v2 = (v2 > 20.f) ? v2 : log1pf(__expf(v2));
            v3 = (v3 > 20.f) ? v3 : log1pf(__expf(v3));
        }
        o.x = v0; o.y = v1; o.z = v2; o.w = v3;
        *(float4*)(C + (row0 + i) * ldc + col0) = o;
    }
}

// ---------------------------------------------------------------------------
// x_proj split-K stage 1: P[ks][(row)*64+col] = A[row, ks*128:+128] . W[col, ...]
// Grid dim3(KS, 64), block 256. A=xc (lda=DI), W=x_proj_w (ldw=DI, 64 rows).
// ---------------------------------------------------------------------------
__global__ __launch_bounds__(256) void xproj_partial(
    const float* __restrict__ A, const float* __restrict__ W,
    float* __restrict__ P)
{
    __shared__ float As[16][68];
    __shared__ float Ws[16][68];

    const int tid  = threadIdx.x;
    const int tx   = tid & 15;
    const int ty   = tid >> 4;
    const int lrow = tid >> 2;
    const int lk   = (tid & 3) << 2;
    const int kbase = blockIdx.x * (DI / KS);

    const float* Ap = A + (blockIdx.y * 64 + lrow) * DI + kbase + lk;
    const float* Wp = W + lrow * DI + kbase + lk;

    float acc[4][4] = {};

    for (int k0 = 0; k0 < DI / KS; k0 += 16) {
        float4 av = *(const float4*)(Ap + k0);
        float4 wv = *(const float4*)(Wp + k0);
        __syncthreads();
        As[lk + 0][lrow] = av.x; As[lk + 1][lrow] = av.y;
        As[lk + 2][lrow] = av.z; As[lk + 3][lrow] = av.w;
        Ws[lk + 0][lrow] = wv.x; Ws[lk + 1][lrow] = wv.y;
        Ws[lk + 2][lrow] = wv.z; Ws[lk + 3][lrow] = wv.w;
        __syncthreads();
#pragma unroll
        for (int k = 0; k < 16; ++k) {
            const float4 a4 = *(const float4*)&As[k][ty << 2];
            const float4 w4 = *(const float4*)&Ws[k][tx << 2];
            acc[0][0] += a4.x * w4.x; acc[0][1] += a4.x * w4.y;
            acc[0][2] += a4.x * w4.z; acc[0][3] += a4.x * w4.w;
            acc[1][0] += a4.y * w4.x; acc[1][1] += a4.y * w4.y;
            acc[1][2] += a4.y * w4.z; acc[1][3] += a4.y * w4.w;
            acc[2][0] += a4.z * w4.x; acc[2][1] += a4.z * w4.y;
            acc[2][2] += a4.z * w4.z; acc[2][3] += a4.z * w4.w;
            acc[3][0] += a4.w * w4.x; acc[3][1] += a4.w * w4.y;
            acc[3][2] += a4.w * w4.z; acc[3][3] += a4.w * w4.w;
        }
    }

    float* out = P + (long)blockIdx.x * (BL * 64)
               + (blockIdx.y * 64 + (ty << 2)) * 64 + (tx << 2);
#pragma unroll
    for (int i = 0; i < 4; ++i)
        *(float4*)(out + i * 64) = make_float4(acc[i][0], acc[i][1],
                                               acc[i][2], acc[i][3]);
}

// ---------------------------------------------------------------------------
// x_proj split-K stage 2: xdbl = sum over KS slices. 256 blocks x 256 thr.
// ---------------------------------------------------------------------------
__global__ __launch_bounds__(256) void xproj_reduce(
    const float* __restrict__ P, float* __restrict__ xdbl)
{
    int i = (blockIdx.x * 256 + threadIdx.x) * 4;
    float4 s = *(const float4*)(P + i);
#pragma unroll
    for (int k = 1; k < KS; ++k) {
        float4 p = *(const float4*)(P + (long)k * (BL * 64) + i);
        s.x += p.x; s.y += p.y; s.z += p.z; s.w += p.w;
    }
    *(float4*)(xdbl + i) = s;
}

// ---------------------------------------------------------------------------
// Causal depthwise conv1d (k=4) + bias + silu.
// ---------------------------------------------------------------------------
__global__ __launch_bounds__(256) void conv_silu(
    const float* __restrict__ xz, const float* __restrict__ cw,
    const float* __restrict__ cb, float* __restrict__ xc)
{
    int idx = blockIdx.x * 256 + threadIdx.x;
    int d  = idx & (DI - 1);
    int bl = idx >> 10;
    int t  = bl & (L_ - 1);
    int base = (bl - t) * (2 * DI) + d;
    float acc = cb[d];
    const float* w = cw + d * 4;
    if (t >= 3) {
        acc += w[0] * xz[base + (t - 3) * (2 * DI)];
        acc += w[1] * xz[base + (t - 2) * (2 * DI)];
        acc += w[2] * xz[base + (t - 1) * (2 * DI)];
        acc += w[3] * xz[base + t * (2 * DI)];
    } else {
#pragma unroll
        for (int j = 0; j < 4; ++j) {
            int tt = t - 3 + j;
            if (tt >= 0) acc += w[j] * xz[base + tt * (2 * DI)];
        }
    }
    xc[idx] = acc / (1.f + __expf(-acc));
}

// ---------------------------------------------------------------------------
template <int CTRL>
__device__ __forceinline__ float dpp_shr_add(float v) {
    int sh = __builtin_amdgcn_update_dpp(0, __float_as_int(v), CTRL, 0xF, 0xF, true);
    return v + __int_as_float(sh);
}

// ---------------------------------------------------------------------------
// Selective scan, LDS-staged. Grid: 512 x 256.
// ---------------------------------------------------------------------------
__global__ __launch_bounds__(256) void scan_kernel(
    const float* __restrict__ dt, const float* __restrict__ xc,
    const float* __restrict__ xdbl, const float* __restrict__ A_log,
    float* __restrict__ ys)
{
    __shared__ float2 sdx[64][17];
    __shared__ float2 sbc[64][17];
    __shared__ float  sy [16][68];

    const int tid  = threadIdx.x;
    const int s    = tid & 15;
    const int grp  = tid >> 4;
    const int bd0  = blockIdx.x * 16;
    const int b    = bd0 >> 10;
    const int d0   = bd0 & (DI - 1);
    const int mbase = b * L_;

    const int d = d0 + grp;
    const float a = -__expf(A_log[d * DS + s]);
    float state = 0.f;

    const int j  = tid & 15;
    const int tt = tid >> 4;

    for (int c = 0; c < L_ / 64; ++c) {
        const int tc = c * 64;
        __syncthreads();
#pragma unroll
        for (int i = 0; i < 4; ++i) {
            int t = tt + 16 * i;
            int m = mbase + tc + t;
            sdx[t][j] = make_float2(dt[m * DI + d0 + j], xc[m * DI + d0 + j]);
            sbc[t][j] = make_float2(xdbl[m * 64 + DTR + j],
                                    xdbl[m * 64 + DTR + DS + j]);
        }
        __syncthreads();

        for (int t4 = 0; t4 < 64; t4 += 4) {
            float ybuf[4];
#pragma unroll
            for (int u = 0; u < 4; ++u) {
                const int t = t4 + u;
                const float2 dx = sdx[t][grp];
                const float2 bc = sbc[t][s];
                const float dA = __expf(dx.x * a);
                state = fmaf(dA, state, dx.x * dx.y * bc.x);
                float contrib = state * bc.y;
                contrib = dpp_shr_add<0x111>(contrib);
                contrib = dpp_shr_add<0x112>(contrib);
                contrib = dpp_shr_add<0x114>(contrib);
                contrib = dpp_shr_add<0x118>(contrib);
                ybuf[u] = contrib;
            }
            if (s == 15) *(float4*)&sy[grp][t4] = *(float4*)ybuf;
        }
        __syncthreads();

#pragma unroll
        for (int i = 0; i < 4; ++i) {
            int t = tt + 16 * i;
            ys[(mbase + tc + t) * DI + d0 + j] = sy[j][t];
        }
    }
}

// ---------------------------------------------------------------------------
// Gate: ysb16 = bf16((ys + xc*Dm) * silu(z))
// ---------------------------------------------------------------------------
__global__ __launch_bounds__(256) void gate_kernel(
    const float* __restrict__ ys, const float* __restrict__ xc,
    const float* __restrict__ Dm, const float* __restrict__ xz,
    unsigned short* __restrict__ ysb16)
{
    int idx = blockIdx.x * 256 + threadIdx.x;
    int d = idx & (DI - 1);
    int m = idx >> 10;
    float z = xz[m * (2 * DI) + DI + d];
    float sz = z / (1.f + __expf(-z));
    ysb16[idx] = f2bf((ys[idx] + xc[idx] * Dm[d]) * sz);
}

// ---------------------------------------------------------------------------
__global__ __launch_bounds__(512) void mean_kernel(
    const float* __restrict__ h, float* __restrict__ hm)
{
    int b = blockIdx.x, d = threadIdx.x;
    float acc = 0.f;
    for (int t = 0; t < L_; ++t) acc += h[(b * L_ + t) * DM + d];
    hm[b * DM + d] = acc * (1.f / (float)L_);
}

// ---------------------------------------------------------------------------
__global__ __launch_bounds__(64) void cls_kernel(
    const float* __restrict__ hm, const float* __restrict__ w1,
    const float* __restrict__ b1, const float* __restrict__ w2,
    const float* __restrict__ b2, float* __restrict__ out)
{
    int b = blockIdx.x, j = threadIdx.x;
    const float* hb = hm + b * DM;
    const float* wr = w1 + j * DM;
    float acc = b1[j];
    for (int k = 0; k < DM; k += 4) {
        acc += hb[k] * wr[k] + hb[k+1] * wr[k+1]
             + hb[k+2] * wr[k+2] + hb[k+3] * wr[k+3];
    }
    acc = fmaxf(acc, 0.f);
    float p = acc * w2[j];
#pragma unroll
    for (int off = 32; off; off >>= 1) p += __shfl_down(p, off);
    if (j == 0) out[b] = p + b2[0];
}

// ---------------------------------------------------------------------------
extern "C" void kernel_launch(void* const* d_in, const int* in_sizes, int n_in,
                              void* d_out, int out_size, void* d_ws, size_t ws_size,
                              hipStream_t stream) {
    const float* x          = (const float*)d_in[0];
    const float* proj_in_w  = (const float*)d_in[1];
    const float* proj_in_b  = (const float*)d_in[2];
    const float* in_proj_w  = (const float*)d_in[3];
    const float* conv_w     = (const float*)d_in[4];
    const float* conv_b     = (const float*)d_in[5];
    const float* x_proj_w   = (const float*)d_in[6];
    const float* dt_proj_w  = (const float*)d_in[7];
    const float* dt_proj_b  = (const float*)d_in[8];
    const float* A_log      = (const float*)d_in[9];
    const float* Dm         = (const float*)d_in[10];
    const float* out_proj_w = (const float*)d_in[11];
    const float* cls_w1     = (const float*)d_in[12];
    const float* cls_b1     = (const float*)d_in[13];
    const float* cls_w2     = (const float*)d_in[14];
    const float* cls_b2     = (const float*)d_in[15];
    float* out = (float*)d_out;

    // fp32 workspace
    float* ws   = (float*)d_ws;
    float* h    = ws;                       // BL*DM      = 2M
    float* xz   = h    + BL * DM;           // BL*2*DI    = 8M
    float* xcb  = xz   + BL * 2 * DI;       // BL*DI      = 4M
    float* xdbl = xcb  + BL * DI;           // BL*64      = 256K
    float* dtb  = xdbl + BL * 64;           // BL*DI      = 4M
    float* ysb  = dtb  + BL * DI;           // BL*DI      = 4M
    float* hm   = ysb  + BL * DI;           // B_*DM      = 4K
    // bf16 (ushort) workspace
    unsigned short* u16  = (unsigned short*)(hm + B_ * DM);
    unsigned short* xbf  = u16;                         // BL*DIN
    unsigned short* hbf  = xbf  + BL * DIN;             // BL*DM
    unsigned short* ysbf = hbf  + BL * DM;              // BL*DI
    unsigned short* wpin = ysbf + BL * DI;              // DM*DIN
    unsigned short* win  = wpin + DM * DIN;             // 2*2DI*DM
    unsigned short* wout = win  + NLAY * 2 * DI * DM;   // 2*DM*DI
    // x_proj split-K partials alias dtb (dead at that point): KS*BL*64 = 2M <= 4M
    float* xpart = dtb;

    f32_to_bf16<<<(BL * DIN) / 2048, 256, 0, stream>>>(x, xbf);
    f32_to_bf16<<<(DM * DIN) / 2048, 256, 0, stream>>>(proj_in_w, wpin);
    f32_to_bf16<<<(NLAY * 2 * DI * DM) / 2048, 256, 0, stream>>>(in_proj_w, win);
    f32_to_bf16<<<(NLAY * DM * DI) / 2048, 256, 0, stream>>>(out_proj_w, wout);

    gemm_mfma<<<dim3(DM / 128, BL / 128), 256, 0, stream>>>(
        xbf, wpin, proj_in_b, h, hbf, DM, DIN);

    for (int l = 0; l < NLAY; ++l) {
        gemm_mfma<<<dim3(2 * DI / 128, BL / 128), 256, 0, stream>>>(
            hbf, win + l * 2 * DI * DM, nullptr, xz, nullptr, 2 * DI, DM);
        conv_silu<<<(BL * DI) / 256, 256, 0, stream>>>(
            xz, conv_w + l * DI * 4, conv_b + l * DI, xcb);
        // x_dbl = xc @ x_proj_w^T  (fp32, split-K)
        xproj_partial<<<dim3(KS, BL / 64), 256, 0, stream>>>(
            xcb, x_proj_w + l * 64 * DI, xpart);
        xproj_reduce<<<(BL * 64) / 1024, 256, 0, stream>>>(xpart, xdbl);
        // dt = softplus(x_dbl[:, :32] @ dt_proj_w^T + dt_b)  (fp32)
        gemm_bias_act<<<dim3(DI / 64, BL / 64), 256, 0, stream>>>(
            xdbl, 64, dt_proj_w + l * DI * DTR, DTR, dt_proj_b + l * DI,
            dtb, DI, DTR, 1);
        scan_kernel<<<(B_ * DI) / 16, 256, 0, stream>>>(
            dtb, xcb, xdbl, A_log + l * DI * DS, ysb);
        gate_kernel<<<(BL * DI) / 256, 256, 0, stream>>>(
            ysb, xcb, Dm + l * DI, xz, ysbf);
        gemm_mfma<<<dim3(DM / 128, BL / 128), 256, 0, stream>>>(
            ysbf, wout + l * DM * DI, nullptr, h, hbf, DM, DI);
    }

    mean_kernel<<<B_, DM, 0, stream>>>(h, hm);
    cls_kernel<<<B_, 64, 0, stream>>>(hm, cls_w1, cls_b1, cls_w2, cls_b2, out);
}

// Round 5
// 392.197 us; speedup vs baseline: 3.1003x; 1.1260x over previous
//
#include <hip/hip_runtime.h>
#include <hip/hip_bf16.h>

// Dims (fixed by the reference)
#define B_   8
#define L_   512
#define DIN  128
#define DM   512
#define NLAY 2
#define DI   1024     // d_inner
#define DS   16       // d_state
#define DTR  32       // dt_rank
#define BL   (B_ * L_)   // 4096
#define KS   8           // x_proj split-K slices

typedef short bf16x8 __attribute__((ext_vector_type(8)));
typedef float floatx4 __attribute__((ext_vector_type(4)));

__device__ __forceinline__ unsigned short f2bf(float f) {
    unsigned int u = __float_as_uint(f);
    unsigned int r = (u + 0x7FFF + ((u >> 16) & 1)) >> 16;   // RNE
    return (unsigned short)r;
}

// ---------------------------------------------------------------------------
// Fused fp32 -> bf16 conversion for x, proj_in_w, in_proj_w, out_proj_w.
// Block ranges (2048 elems/block): [0,256) [256,288) [288,1312) [1312,1824)
// ---------------------------------------------------------------------------
__global__ __launch_bounds__(256) void cvt_all(
    const float* __restrict__ x,  unsigned short* __restrict__ xbf,
    const float* __restrict__ pw, unsigned short* __restrict__ wpin,
    const float* __restrict__ iw, unsigned short* __restrict__ win,
    const float* __restrict__ ow, unsigned short* __restrict__ wout)
{
    int bid = blockIdx.x;
    const float* src; unsigned short* dst; int off;
    if      (bid < 256)  { src = x;  dst = xbf;  off = bid; }
    else if (bid < 288)  { src = pw; dst = wpin; off = bid - 256; }
    else if (bid < 1312) { src = iw; dst = win;  off = bid - 288; }
    else                 { src = ow; dst = wout; off = bid - 1312; }
    int i = (off * 256 + threadIdx.x) * 8;
    float4 a = *(const float4*)(src + i);
    float4 b = *(const float4*)(src + i + 4);
    unsigned short o[8];
    o[0] = f2bf(a.x); o[1] = f2bf(a.y); o[2] = f2bf(a.z); o[3] = f2bf(a.w);
    o[4] = f2bf(b.x); o[5] = f2bf(b.y); o[6] = f2bf(b.z); o[7] = f2bf(b.w);
    *(uint4*)(dst + i) = *(uint4*)o;
}

// ---------------------------------------------------------------------------
// bf16 MFMA GEMM, tile 128x128, BK=32 (for N=2048 in_proj).
// ---------------------------------------------------------------------------
__global__ __launch_bounds__(256) void gemm_mfma(
    const unsigned short* __restrict__ A,
    const unsigned short* __restrict__ W,
    const float* __restrict__ bias,
    float* __restrict__ C, unsigned short* __restrict__ Cb,
    int N, int K)
{
    __shared__ unsigned short As[128 * 40];
    __shared__ unsigned short Ws[128 * 40];

    const int tid  = threadIdx.x;
    const int row  = tid >> 1;
    const int half = tid & 1;
    const long aBase = (long)(blockIdx.y * 128 + row) * K + half * 16;
    const long wBase = (long)(blockIdx.x * 128 + row) * K + half * 16;
    const int  lbase = row * 40 + half * 16;

    const int lane = tid & 63;
    const int wv   = tid >> 6;
    const int wm   = (wv >> 1) * 64;
    const int wn   = (wv & 1) * 64;
    const int lr   = lane & 15;
    const int q    = lane >> 4;

    floatx4 acc[4][4];
#pragma unroll
    for (int i = 0; i < 4; ++i)
#pragma unroll
        for (int j = 0; j < 4; ++j)
#pragma unroll
            for (int r = 0; r < 4; ++r) acc[i][j][r] = 0.f;

    for (int k0 = 0; k0 < K; k0 += 32) {
        __syncthreads();
        const unsigned short* ap = A + aBase + k0;
        const unsigned short* wp = W + wBase + k0;
        uint4 a0 = *(const uint4*)ap;
        uint4 a1 = *(const uint4*)(ap + 8);
        uint4 w0 = *(const uint4*)wp;
        uint4 w1 = *(const uint4*)(wp + 8);
        *(uint4*)(As + lbase)     = a0;
        *(uint4*)(As + lbase + 8) = a1;
        *(uint4*)(Ws + lbase)     = w0;
        *(uint4*)(Ws + lbase + 8) = w1;
        __syncthreads();

        bf16x8 af[4], bfr[4];
#pragma unroll
        for (int i = 0; i < 4; ++i)
            af[i] = *(const bf16x8*)(As + (wm + i * 16 + lr) * 40 + q * 8);
#pragma unroll
        for (int j = 0; j < 4; ++j)
            bfr[j] = *(const bf16x8*)(Ws + (wn + j * 16 + lr) * 40 + q * 8);
#pragma unroll
        for (int i = 0; i < 4; ++i)
#pragma unroll
            for (int j = 0; j < 4; ++j)
                acc[i][j] = __builtin_amdgcn_mfma_f32_16x16x32_bf16(
                    af[i], bfr[j], acc[i][j], 0, 0, 0);
    }

#pragma unroll
    for (int i = 0; i < 4; ++i) {
#pragma unroll
        for (int r = 0; r < 4; ++r) {
            const int  crow = blockIdx.y * 128 + wm + i * 16 + q * 4 + r;
            const long base = (long)crow * N + blockIdx.x * 128 + wn + lr;
#pragma unroll
            for (int j = 0; j < 4; ++j) {
                float v = acc[i][j][r];
                C[base + j * 16] = v;
                if (Cb) Cb[base + j * 16] = f2bf(v);
            }
        }
    }
}

// ---------------------------------------------------------------------------
// bf16 MFMA GEMM, tile 128(M)x64(N), BK=32 — for N=512 (proj_in, out_proj):
// grid (N/64, M/128) = 256 blocks = full machine. 4 waves, each 32x64.
// ---------------------------------------------------------------------------
__global__ __launch_bounds__(256) void gemm_mfma_n64(
    const unsigned short* __restrict__ A,
    const unsigned short* __restrict__ W,
    const float* __restrict__ bias,
    float* __restrict__ C, unsigned short* __restrict__ Cb,
    int N, int K)
{
    __shared__ unsigned short As[128 * 40];
    __shared__ unsigned short Ws[64 * 40];

    const int tid   = threadIdx.x;
    const int arow  = tid >> 1;
    const int ahalf = tid & 1;
    const long aBase = (long)(blockIdx.y * 128 + arow) * K + ahalf * 16;
    const int  albase = arow * 40 + ahalf * 16;
    const int wrow = tid >> 2;
    const int wq   = tid & 3;
    const long wBase = (long)(blockIdx.x * 64 + wrow) * K + wq * 8;
    const int  wlbase = wrow * 40 + wq * 8;

    const int lane = tid & 63;
    const int wv   = tid >> 6;
    const int wm   = wv * 32;
    const int lr   = lane & 15;
    const int q    = lane >> 4;

    floatx4 acc[2][4];
#pragma unroll
    for (int i = 0; i < 2; ++i)
#pragma unroll
        for (int j = 0; j < 4; ++j)
#pragma unroll
            for (int r = 0; r < 4; ++r) acc[i][j][r] = 0.f;

    for (int k0 = 0; k0 < K; k0 += 32) {
        __syncthreads();
        const unsigned short* ap = A + aBase + k0;
        uint4 a0 = *(const uint4*)ap;
        uint4 a1 = *(const uint4*)(ap + 8);
        uint4 w0 = *(const uint4*)(W + wBase + k0);
        *(uint4*)(As + albase)     = a0;
        *(uint4*)(As + albase + 8) = a1;
        *(uint4*)(Ws + wlbase)     = w0;
        __syncthreads();

        bf16x8 af[2], bfr[4];
#pragma unroll
        for (int i = 0; i < 2; ++i)
            af[i] = *(const bf16x8*)(As + (wm + i * 16 + lr) * 40 + q * 8);
#pragma unroll
        for (int j = 0; j < 4; ++j)
            bfr[j] = *(const bf16x8*)(Ws + (j * 16 + lr) * 40 + q * 8);
#pragma unroll
        for (int i = 0; i < 2; ++i)
#pragma unroll
            for (int j = 0; j < 4; ++j)
                acc[i][j] = __builtin_amdgcn_mfma_f32_16x16x32_bf16(
                    af[i], bfr[j], acc[i][j], 0, 0, 0);
    }

    float bj[4] = {0.f, 0.f, 0.f, 0.f};
    if (bias) {
#pragma unroll
        for (int j = 0; j < 4; ++j)
            bj[j] = bias[blockIdx.x * 64 + j * 16 + lr];
    }
#pragma unroll
    for (int i = 0; i < 2; ++i) {
#pragma unroll
        for (int r = 0; r < 4; ++r) {
            const int  crow = blockIdx.y * 128 + wm + i * 16 + q * 4 + r;
            const long base = (long)crow * N + blockIdx.x * 64 + lr;
#pragma unroll
            for (int j = 0; j < 4; ++j) {
                float v = acc[i][j][r] + bj[j];
                C[base + j * 16] = v;
                if (Cb) Cb[base + j * 16] = f2bf(v);
            }
        }
    }
}

// ---------------------------------------------------------------------------
// fp32 GEMM (small mats): C[M,N] = A[M,K]*W[N,K]^T (+bias)(+softplus act==1)
// ---------------------------------------------------------------------------
__global__ __launch_bounds__(256) void gemm_bias_act(
    const float* __restrict__ A, int lda,
    const float* __restrict__ W, int ldw,
    const float* __restrict__ bias,
    float* __restrict__ C, int ldc,
    int K, int act)
{
    __shared__ float As[16][68];
    __shared__ float Ws[16][68];

    const int tid  = threadIdx.x;
    const int tx   = tid & 15;
    const int ty   = tid >> 4;
    const int lrow = tid >> 2;
    const int lk   = (tid & 3) << 2;

    const float* Ap = A + (blockIdx.y * 64 + lrow) * lda + lk;
    const float* Wp = W + (blockIdx.x * 64 + lrow) * ldw + lk;

    float acc[4][4] = {};

    for (int k0 = 0; k0 < K; k0 += 16) {
        float4 av = *(const float4*)(Ap + k0);
        float4 wv = *(const float4*)(Wp + k0);
        As[lk + 0][lrow] = av.x; As[lk + 1][lrow] = av.y;
        As[lk + 2][lrow] = av.z; As[lk + 3][lrow] = av.w;
        Ws[lk + 0][lrow] = wv.x; Ws[lk + 1][lrow] = wv.y;
        Ws[lk + 2][lrow] = wv.z; Ws[lk + 3][lrow] = wv.w;
        __syncthreads();
#pragma unroll
        for (int k = 0; k < 16; ++k) {
            const float4 a4 = *(const float4*)&As[k][ty << 2];
            const float4 w4 = *(const float4*)&Ws[k][tx << 2];
            acc[0][0] += a4.x * w4.x; acc[0][1] += a4.x * w4.y;
            acc[0][2] += a4.x * w4.z; acc[0][3] += a4.x * w4.w;
            acc[1][0] += a4.y * w4.x; acc[1][1] += a4.y * w4.y;
            acc[1][2] += a4.y * w4.z; acc[1][3] += a4.y * w4.w;
            acc[2][0] += a4.z * w4.x; acc[2][1] += a4.z * w4.y;
            acc[2][2] += a4.z * w4.z; acc[2][3] += a4.z * w4.w;
            acc[3][0] += a4.w * w4.x; acc[3][1] += a4.w * w4.y;
            acc[3][2] += a4.w * w4.z; acc[3][3] += a4.w * w4.w;
        }
        __syncthreads();
    }

    const int row0 = blockIdx.y * 64 + (ty << 2);
    const int col0 = blockIdx.x * 64 + (tx << 2);
    float bi[4] = {0.f, 0.f, 0.f, 0.f};
    if (bias) {
        bi[0] = bias[col0 + 0]; bi[1] = bias[col0 + 1];
        bi[2] = bias[col0 + 2]; bi[3] = bias[col0 + 3];
    }
#pragma unroll
    for (int i = 0; i < 4; ++i) {
        float4 o;
        float v0 = acc[i][0] + bi[0];
        float v1 = acc[i][1] + bi[1];
        float v2 = acc[i][2] + bi[2];
        float v3 = acc[i][3] + bi[3];
        if (act == 1) {
            v0 = (v0 > 20.f) ? v0 : log1pf(__expf(v0));
            v1 = (v1 > 20.f) ? v1 : log1pf(__expf(v1));
            v2 = (v2 > 20.f) ? v2 : log1pf(__expf(v2));
            v3 = (v3 > 20.f) ? v3 : log1pf(__expf(v3));
        }
        o.x = v0; o.y = v1; o.z = v2; o.w = v3;
        *(float4*)(C + (row0 + i) * ldc + col0) = o;
    }
}

// ---------------------------------------------------------------------------
// x_proj split-K stage 1 + stage 2
// ---------------------------------------------------------------------------
__global__ __launch_bounds__(256) void xproj_partial(
    const float* __restrict__ A, const float* __restrict__ W,
    float* __restrict__ P)
{
    __shared__ float As[16][68];
    __shared__ float Ws[16][68];

    const int tid  = threadIdx.x;
    const int tx   = tid & 15;
    const int ty   = tid >> 4;
    const int lrow = tid >> 2;
    const int lk   = (tid & 3) << 2;
    const int kbase = blockIdx.x * (DI / KS);

    const float* Ap = A + (blockIdx.y * 64 + lrow) * DI + kbase + lk;
    const float* Wp = W + lrow * DI + kbase + lk;

    float acc[4][4] = {};

    for (int k0 = 0; k0 < DI / KS; k0 += 16) {
        float4 av = *(const float4*)(Ap + k0);
        float4 wv = *(const float4*)(Wp + k0);
        __syncthreads();
        As[lk + 0][lrow] = av.x; As[lk + 1][lrow] = av.y;
        As[lk + 2][lrow] = av.z; As[lk + 3][lrow] = av.w;
        Ws[lk + 0][lrow] = wv.x; Ws[lk + 1][lrow] = wv.y;
        Ws[lk + 2][lrow] = wv.z; Ws[lk + 3][lrow] = wv.w;
        __syncthreads();
#pragma unroll
        for (int k = 0; k < 16; ++k) {
            const float4 a4 = *(const float4*)&As[k][ty << 2];
            const float4 w4 = *(const float4*)&Ws[k][tx << 2];
            acc[0][0] += a4.x * w4.x; acc[0][1] += a4.x * w4.y;
            acc[0][2] += a4.x * w4.z; acc[0][3] += a4.x * w4.w;
            acc[1][0] += a4.y * w4.x; acc[1][1] += a4.y * w4.y;
            acc[1][2] += a4.y * w4.z; acc[1][3] += a4.y * w4.w;
            acc[2][0] += a4.z * w4.x; acc[2][1] += a4.z * w4.y;
            acc[2][2] += a4.z * w4.z; acc[2][3] += a4.z * w4.w;
            acc[3][0] += a4.w * w4.x; acc[3][1] += a4.w * w4.y;
            acc[3][2] += a4.w * w4.z; acc[3][3] += a4.w * w4.w;
        }
    }

    float* out = P + (long)blockIdx.x * (BL * 64)
               + (blockIdx.y * 64 + (ty << 2)) * 64 + (tx << 2);
#pragma unroll
    for (int i = 0; i < 4; ++i)
        *(float4*)(out + i * 64) = make_float4(acc[i][0], acc[i][1],
                                               acc[i][2], acc[i][3]);
}

__global__ __launch_bounds__(256) void xproj_reduce(
    const float* __restrict__ P, float* __restrict__ xdbl)
{
    int i = (blockIdx.x * 256 + threadIdx.x) * 4;
    float4 s = *(const float4*)(P + i);
#pragma unroll
    for (int k = 1; k < KS; ++k) {
        float4 p = *(const float4*)(P + (long)k * (BL * 64) + i);
        s.x += p.x; s.y += p.y; s.z += p.z; s.w += p.w;
    }
    *(float4*)(xdbl + i) = s;
}

// ---------------------------------------------------------------------------
// Causal depthwise conv1d (k=4) + bias + silu.
// ---------------------------------------------------------------------------
__global__ __launch_bounds__(256) void conv_silu(
    const float* __restrict__ xz, const float* __restrict__ cw,
    const float* __restrict__ cb, float* __restrict__ xc)
{
    int idx = blockIdx.x * 256 + threadIdx.x;
    int d  = idx & (DI - 1);
    int bl = idx >> 10;
    int t  = bl & (L_ - 1);
    int base = (bl - t) * (2 * DI) + d;
    float acc = cb[d];
    const float* w = cw + d * 4;
    if (t >= 3) {
        acc += w[0] * xz[base + (t - 3) * (2 * DI)];
        acc += w[1] * xz[base + (t - 2) * (2 * DI)];
        acc += w[2] * xz[base + (t - 1) * (2 * DI)];
        acc += w[3] * xz[base + t * (2 * DI)];
    } else {
#pragma unroll
        for (int j = 0; j < 4; ++j) {
            int tt = t - 3 + j;
            if (tt >= 0) acc += w[j] * xz[base + tt * (2 * DI)];
        }
    }
    xc[idx] = acc / (1.f + __expf(-acc));
}

// ---------------------------------------------------------------------------
template <int CTRL>
__device__ __forceinline__ float dpp_shr_add(float v) {
    int sh = __builtin_amdgcn_update_dpp(0, __float_as_int(v), CTRL, 0xF, 0xF, true);
    return v + __int_as_float(sh);
}

// ---------------------------------------------------------------------------
// Selective scan + fused gate/D-skip/bf16 output.
// ysb16 = bf16((scan_y + xc*Dm) * silu(z)). Grid: 512 x 256.
// ---------------------------------------------------------------------------
__global__ __launch_bounds__(256) void scan_gate_kernel(
    const float* __restrict__ dt, const float* __restrict__ xc,
    const float* __restrict__ xdbl, const float* __restrict__ A_log,
    const float* __restrict__ Dm, const float* __restrict__ xz,
    unsigned short* __restrict__ ysb16)
{
    __shared__ float2 sdx[64][17];   // (dt, xc)
    __shared__ float2 sbc[64][17];   // (B, C)
    __shared__ float  sy [16][68];

    const int tid  = threadIdx.x;
    const int s    = tid & 15;
    const int grp  = tid >> 4;
    const int bd0  = blockIdx.x * 16;
    const int b    = bd0 >> 10;
    const int d0   = bd0 & (DI - 1);
    const int mbase = b * L_;

    const int d = d0 + grp;
    const float a = -__expf(A_log[d * DS + s]);
    float state = 0.f;

    const int j  = tid & 15;         // store/load column
    const int tt = tid >> 4;
    const float dmv = Dm[d0 + j];

    for (int c = 0; c < L_ / 64; ++c) {
        const int tc = c * 64;
        __syncthreads();
#pragma unroll
        for (int i = 0; i < 4; ++i) {
            int t = tt + 16 * i;
            int m = mbase + tc + t;
            sdx[t][j] = make_float2(dt[m * DI + d0 + j], xc[m * DI + d0 + j]);
            sbc[t][j] = make_float2(xdbl[m * 64 + DTR + j],
                                    xdbl[m * 64 + DTR + DS + j]);
        }
        __syncthreads();

        for (int t4 = 0; t4 < 64; t4 += 4) {
            float ybuf[4];
#pragma unroll
            for (int u = 0; u < 4; ++u) {
                const int t = t4 + u;
                const float2 dx = sdx[t][grp];
                const float2 bc = sbc[t][s];
                const float dA = __expf(dx.x * a);
                state = fmaf(dA, state, dx.x * dx.y * bc.x);
                float contrib = state * bc.y;
                contrib = dpp_shr_add<0x111>(contrib);
                contrib = dpp_shr_add<0x112>(contrib);
                contrib = dpp_shr_add<0x114>(contrib);
                contrib = dpp_shr_add<0x118>(contrib);
                ybuf[u] = contrib;
            }
            if (s == 15) *(float4*)&sy[grp][t4] = *(float4*)ybuf;
        }
        __syncthreads();

        // fused gate: (y + xc*Dm) * silu(z) -> bf16, coalesced per chunk
#pragma unroll
        for (int i = 0; i < 4; ++i) {
            int t = tt + 16 * i;
            int m = mbase + tc + t;
            float z = xz[m * (2 * DI) + DI + d0 + j];
            float sz = z / (1.f + __expf(-z));
            float val = (sy[j][t] + sdx[t][j].y * dmv) * sz;
            ysb16[m * DI + d0 + j] = f2bf(val);
        }
    }
}

// ---------------------------------------------------------------------------
// Mean over L, two stages.
// ---------------------------------------------------------------------------
__global__ __launch_bounds__(512) void mean_partial(
    const float* __restrict__ h, float* __restrict__ hmp)
{
    int b = blockIdx.x >> 3, sl = blockIdx.x & 7, d = threadIdx.x;
    float acc = 0.f;
    int t0 = sl * 64;
    for (int t = 0; t < 64; ++t) acc += h[(b * L_ + t0 + t) * DM + d];
    hmp[blockIdx.x * DM + d] = acc;
}

__global__ __launch_bounds__(256) void mean_final(
    const float* __restrict__ hmp, float* __restrict__ hm)
{
    int idx = blockIdx.x * 256 + threadIdx.x;   // B_*DM = 4096
    int b = idx >> 9, d = idx & (DM - 1);
    float acc = 0.f;
#pragma unroll
    for (int sl = 0; sl < 8; ++sl) acc += hmp[(b * 8 + sl) * DM + d];
    hm[idx] = acc * (1.f / (float)L_);
}

// ---------------------------------------------------------------------------
__global__ __launch_bounds__(64) void cls_kernel(
    const float* __restrict__ hm, const float* __restrict__ w1,
    const float* __restrict__ b1, const float* __restrict__ w2,
    const float* __restrict__ b2, float* __restrict__ out)
{
    int b = blockIdx.x, j = threadIdx.x;
    const float* hb = hm + b * DM;
    const float* wr = w1 + j * DM;
    float acc = b1[j];
    for (int k = 0; k < DM; k += 4) {
        acc += hb[k] * wr[k] + hb[k+1] * wr[k+1]
             + hb[k+2] * wr[k+2] + hb[k+3] * wr[k+3];
    }
    acc = fmaxf(acc, 0.f);
    float p = acc * w2[j];
#pragma unroll
    for (int off = 32; off; off >>= 1) p += __shfl_down(p, off);
    if (j == 0) out[b] = p + b2[0];
}

// ---------------------------------------------------------------------------
extern "C" void kernel_launch(void* const* d_in, const int* in_sizes, int n_in,
                              void* d_out, int out_size, void* d_ws, size_t ws_size,
                              hipStream_t stream) {
    const float* x          = (const float*)d_in[0];
    const float* proj_in_w  = (const float*)d_in[1];
    const float* proj_in_b  = (const float*)d_in[2];
    const float* in_proj_w  = (const float*)d_in[3];
    const float* conv_w     = (const float*)d_in[4];
    const float* conv_b     = (const float*)d_in[5];
    const float* x_proj_w   = (const float*)d_in[6];
    const float* dt_proj_w  = (const float*)d_in[7];
    const float* dt_proj_b  = (const float*)d_in[8];
    const float* A_log      = (const float*)d_in[9];
    const float* Dm         = (const float*)d_in[10];
    const float* out_proj_w = (const float*)d_in[11];
    const float* cls_w1     = (const float*)d_in[12];
    const float* cls_b1     = (const float*)d_in[13];
    const float* cls_w2     = (const float*)d_in[14];
    const float* cls_b2     = (const float*)d_in[15];
    float* out = (float*)d_out;

    // fp32 workspace
    float* ws   = (float*)d_ws;
    float* h    = ws;                       // BL*DM
    float* xz   = h    + BL * DM;           // BL*2*DI
    float* xcb  = xz   + BL * 2 * DI;       // BL*DI
    float* xdbl = xcb  + BL * DI;           // BL*64
    float* dtb  = xdbl + BL * 64;           // BL*DI
    float* ysb  = dtb  + BL * DI;           // BL*DI (unused now, keeps layout)
    float* hm   = ysb  + BL * DI;           // B_*DM
    float* hmp  = hm   + B_ * DM;           // 64*DM partials
    // bf16 (ushort) workspace
    unsigned short* u16  = (unsigned short*)(hmp + 64 * DM);
    unsigned short* xbf  = u16;                         // BL*DIN
    unsigned short* hbf  = xbf  + BL * DIN;             // BL*DM
    unsigned short* ysbf = hbf  + BL * DM;              // BL*DI
    unsigned short* wpin = ysbf + BL * DI;              // DM*DIN
    unsigned short* win  = wpin + DM * DIN;             // NLAY*2DI*DM
    unsigned short* wout = win  + NLAY * 2 * DI * DM;   // NLAY*DM*DI
    // x_proj split-K partials alias dtb-region? dtb live during scan; alias ysb (dead)
    float* xpart = ysb;   // KS*BL*64 = 2M floats <= 4M

    cvt_all<<<1824, 256, 0, stream>>>(x, xbf, proj_in_w, wpin,
                                      in_proj_w, win, out_proj_w, wout);

    // h = x @ proj_in_w^T + b  (N64 MFMA, 256 blocks, dual write)
    gemm_mfma_n64<<<dim3(DM / 64, BL / 128), 256, 0, stream>>>(
        xbf, wpin, proj_in_b, h, hbf, DM, DIN);

    for (int l = 0; l < NLAY; ++l) {
        gemm_mfma<<<dim3(2 * DI / 128, BL / 128), 256, 0, stream>>>(
            hbf, win + l * 2 * DI * DM, nullptr, xz, nullptr, 2 * DI, DM);
        conv_silu<<<(BL * DI) / 256, 256, 0, stream>>>(
            xz, conv_w + l * DI * 4, conv_b + l * DI, xcb);
        xproj_partial<<<dim3(KS, BL / 64), 256, 0, stream>>>(
            xcb, x_proj_w + l * 64 * DI, xpart);
        xproj_reduce<<<(BL * 64) / 1024, 256, 0, stream>>>(xpart, xdbl);
        gemm_bias_act<<<dim3(DI / 64, BL / 64), 256, 0, stream>>>(
            xdbl, 64, dt_proj_w + l * DI * DTR, DTR, dt_proj_b + l * DI,
            dtb, DI, DTR, 1);
        scan_gate_kernel<<<(B_ * DI) / 16, 256, 0, stream>>>(
            dtb, xcb, xdbl, A_log + l * DI * DS, Dm + l * DI, xz, ysbf);
        gemm_mfma_n64<<<dim3(DM / 64, BL / 128), 256, 0, stream>>>(
            ysbf, wout + l * DM * DI, nullptr, h, hbf, DM, DI);
    }

    mean_partial<<<B_ * 8, DM, 0, stream>>>(h, hmp);
    mean_final<<<(B_ * DM) / 256, 256, 0, stream>>>(hmp, hm);
    cls_kernel<<<B_, 64, 0, stream>>>(hm, cls_w1, cls_b1, cls_w2, cls_b2, out);
}